// Round 15
// baseline (149.600 us; speedup 1.0000x reference)
//
#include <hip/hip_runtime.h>
#include <hip/hip_bf16.h>
#include <cstdint>
#include <cstddef>

// ---------------------------------------------------------------------------
// GraphSAGE 2-layer forward (mean aggregator), MI355X / gfx950.
//
//   h  = relu(x @ Ws1.T + mean_nbr1(x) @ Wn1.T + b1)
//   out = h @ Ws2.T + mean_nbr2(h) @ Wn2.T + b2
//
// Structure (round 15):
//   k_prep:  xcat[:,0:128]=bf16(x); w1f/w2f frag-major bf16; per-chunk LDS
//            bucket histograms (dst>>9, 196 buckets x 64 chunks)
//   scans:   k_scan_block + k_scan_addsums (merged sums-scan)
//   k_scat:  LDS-cursor scatter -> bucketed u32 (src | (dst&511)<<20).
//            COARSER GEOMETRY: ~48-edge runs per (bucket,chunk) = 192B
//            contiguous writes (was 12 edges/48B -> partial-line RMW)
//   k_bcsr:  512-thr per-bucket LDS counting sort -> CSR + rowptr
//   k_agg1:  xcat[:,128:256] = bf16(mean1(x)); 4-way unrolled gather
//   k_fused: ROUND-13 VERBATIM (best measured 41us): 64-row tile, 4 waves,
//            32KB LDS, depth-2 register pipeline, swapped-operand MFMA
//   k_agg2fin: out += mean2(p); 4-way unrolled bf16 gather
//
// Round-1: fp32-atomic scatter = atomic-bound -> CSR gather.
// Round-3: global-atomic CSR fill = HBM RMW -> LDS counting sort.
// Round-5..14: k_fused CONVERGED: ten structural variants (L2/LDS weights,
//   2-8 waves, 0-3 barriers, 64-256 rows, reg pipelines) all 41-47us;
//   MfmaUtil*dur == 6.3us == compute floor in every one. r13 best (41us).
//   Amdahl: remaining 95us is the build+gather pipeline -> this round
//   coarsens the sort geometry (512-node buckets, 64 chunks) to kill
//   k_scat's partial-line write amplification.
// ---------------------------------------------------------------------------

#define D_IN 128
#define D_H  256
#define D_C  40

#define NBLK     64       // chunks per layer
#define BKT_SH   9        // bucket = dst >> 9 (512 nodes)
#define NBKT_MAX 200      // ceil(100000/512) = 196
#define BKT_CAP  4608     // max edges per bucket (mean 3072, sd ~55)

typedef __bf16 bf16_t;
typedef __attribute__((ext_vector_type(8))) __bf16 bf16x8;
typedef __attribute__((ext_vector_type(4))) __bf16 bf16x4;
typedef __attribute__((ext_vector_type(4))) float  f32x4;

// ---------------- ws layout (bytes), 256B-aligned ----------------
static constexpr size_t NMAX = 100000;
static constexpr size_t EMAX = 600000;
static constexpr size_t NSC_MAX = (size_t)NBKT_MAX * NBLK;
static constexpr size_t alignup(size_t v) { return (v + 255) & ~size_t(255); }

static constexpr size_t HG1_OFF  = 0;
static constexpr size_t HG2_OFF  = alignup(HG1_OFF + NSC_MAX * 4);
static constexpr size_t BS1_OFF  = alignup(HG2_OFF + NSC_MAX * 4);
static constexpr size_t BS2_OFF  = alignup(BS1_OFF + 512 * 4);
static constexpr size_t RP1_OFF  = alignup(BS2_OFF + 512 * 4);
static constexpr size_t RP2_OFF  = alignup(RP1_OFF + (NMAX + 1) * 4);
static constexpr size_t BKT1_OFF = alignup(RP2_OFF + (NMAX + 1) * 4);
static constexpr size_t BKT2_OFF = alignup(BKT1_OFF + EMAX * 4);
static constexpr size_t XCAT_OFF = alignup(BKT2_OFF + EMAX * 4);        // bf16[N+64][256]
static constexpr size_t P_OFF    = alignup(XCAT_OFF + (NMAX + 64) * 256 * 2); // bf16[N][40]
static constexpr size_t W1F_OFF  = alignup(P_OFF + NMAX * 40 * 2);
static constexpr size_t W2F_OFF  = alignup(W1F_OFF + 32 * 256 * 8 * 2);
static constexpr size_t WS_NEEDED = W2F_OFF + 32 * 80 * 8 * 2;

// ---------------- merged prep: convx + conv_w + hist ----------------
__global__ __launch_bounds__(256) void k_prep(
    const float* __restrict__ x, bf16_t* __restrict__ xcat,
    const float* __restrict__ ws1, const float* __restrict__ wn1,
    const float* __restrict__ ws2, const float* __restrict__ wn2,
    bf16_t* __restrict__ w1f, bf16_t* __restrict__ w2f,
    const int* __restrict__ dst1, const int* __restrict__ dst2,
    int* __restrict__ hg1, int* __restrict__ hg2,
    int N, int E, int chunk, int nbkt, int nconvx) {
  __shared__ int h[NBKT_MAX];
  int bid = blockIdx.x;

  if (bid < nconvx) {
    int t = bid * 256 + threadIdx.x;
    if (t < N * 16) {
      int row = t >> 4, j = t & 15;
      const float* sp = x + (size_t)row * 128 + j * 8;
      float4 v0 = ((const float4*)sp)[0];
      float4 v1 = ((const float4*)sp)[1];
      bf16x8 o;
      o[0] = (bf16_t)v0.x; o[1] = (bf16_t)v0.y; o[2] = (bf16_t)v0.z; o[3] = (bf16_t)v0.w;
      o[4] = (bf16_t)v1.x; o[5] = (bf16_t)v1.y; o[6] = (bf16_t)v1.z; o[7] = (bf16_t)v1.w;
      *(bf16x8*)(xcat + (size_t)row * 256 + j * 8) = o;
    }
    return;
  }
  bid -= nconvx;

  if (bid < 32) {
    int t = bid * 256 + threadIdx.x;
    {
      int ks4g = t >> 8, col = t & 255;
      int k0 = (ks4g >> 2) * 32 + (ks4g & 3) * 8;
      bf16x8 o;
#pragma unroll
      for (int i = 0; i < 8; ++i) {
        int k = k0 + i;   // K-concat: k<128 -> Ws1, else Wn1
        float v = (k < 128) ? ws1[col * 128 + k] : wn1[col * 128 + (k - 128)];
        o[i] = (bf16_t)v;
      }
      *(bf16x8*)(w1f + (size_t)t * 8) = o;
    }
    if (t < 32 * 80) {
      int ks4g = t / 80, col = t - ks4g * 80;
      int k0 = (ks4g >> 2) * 32 + (ks4g & 3) * 8;
      bf16x8 o;
#pragma unroll
      for (int i = 0; i < 8; ++i) {
        int k = k0 + i;   // col-concat: col<40 -> Ws2, else Wn2
        float v = (col < 40) ? ws2[col * 256 + k] : wn2[(col - 40) * 256 + k];
        o[i] = (bf16_t)v;
      }
      *(bf16x8*)(w2f + (size_t)t * 8) = o;
    }
    return;
  }
  bid -= 32;                                 // hist: bid in [0, 2*NBLK)
  {
    const int* dst = (bid >= NBLK) ? dst2 : dst1;
    int*       hg  = (bid >= NBLK) ? hg2 : hg1;
    int        cb  = bid & (NBLK - 1);
    for (int i = threadIdx.x; i < nbkt; i += 256) h[i] = 0;
    __syncthreads();
    int beg = cb * chunk, end = min(E, beg + chunk);
    for (int e = beg + threadIdx.x; e < end; e += 256)
      atomicAdd(&h[dst[e] >> BKT_SH], 1);
    __syncthreads();
    for (int b = threadIdx.x; b < nbkt; b += 256)
      hg[b * NBLK + cb] = h[b];   // bucket-major, chunk-minor
  }
}

// ---------------- scan pass 1 ----------------
__global__ void k_scan_block(int* __restrict__ a1, int* __restrict__ a2,
                             int* __restrict__ b1s, int* __restrict__ b2s, int n) {
  int* a    = blockIdx.y ? a2 : a1;
  int* bsum = blockIdx.y ? b2s : b1s;
  __shared__ int lds[256];
  int t = threadIdx.x, i = blockIdx.x * 256 + t;
  int v = (i < n) ? a[i] : 0;
  lds[t] = v;
  __syncthreads();
  for (int off = 1; off < 256; off <<= 1) {
    int add = (t >= off) ? lds[t - off] : 0;
    __syncthreads();
    lds[t] += add;
    __syncthreads();
  }
  if (i < n) a[i] = lds[t] - v;
  if (t == 255) bsum[blockIdx.x] = lds[255];
}

// ---------------- scan pass 2 (merged sums-scan + add) ----------------
__global__ void k_scan_addsums(int* __restrict__ a1, int* __restrict__ a2,
                               const int* __restrict__ b1s, const int* __restrict__ b2s,
                               int n, int nb) {
  int* a          = blockIdx.y ? a2 : a1;
  const int* bsum = blockIdx.y ? b2s : b1s;
  __shared__ int lds[256];
  int t = threadIdx.x;
  int v = (t < nb) ? bsum[t] : 0;
  lds[t] = v;
  __syncthreads();
  for (int off = 1; off < 256; off <<= 1) {
    int add = (t >= off) ? lds[t - off] : 0;
    __syncthreads();
    lds[t] += add;
    __syncthreads();
  }
  __shared__ int excl[256];
  excl[t] = lds[t] - v;
  __syncthreads();
  int i = blockIdx.x * 256 + t;
  if (i < n) a[i] += excl[i >> 8];
}

// ---------------- scatter into bucketed array (LDS cursors) ----------------
// value: src | (dst & 511) << 20   (src < 2^20)
__global__ void k_scat(const int* __restrict__ src1, const int* __restrict__ dst1,
                       const int* __restrict__ src2, const int* __restrict__ dst2,
                       const int* __restrict__ off1, const int* __restrict__ off2,
                       unsigned* __restrict__ bkt1, unsigned* __restrict__ bkt2,
                       int E, int chunk, int nbkt) {
  const int* src = blockIdx.y ? src2 : src1;
  const int* dst = blockIdx.y ? dst2 : dst1;
  const int* off = blockIdx.y ? off2 : off1;
  unsigned*  bkt = blockIdx.y ? bkt2 : bkt1;
  __shared__ int cur[NBKT_MAX];
  for (int i = threadIdx.x; i < nbkt; i += 256)
    cur[i] = off[i * NBLK + blockIdx.x];
  __syncthreads();
  int beg = blockIdx.x * chunk, end = min(E, beg + chunk);
  for (int e = beg + threadIdx.x; e < end; e += 256) {
    int d = dst[e];
    int slot = atomicAdd(&cur[d >> BKT_SH], 1);
    bkt[slot] = (unsigned)src[e] | ((unsigned)(d & 511) << 20);
  }
}

// ---------------- per-bucket LDS counting sort -> CSR + rowptr (512 thr) -----
__global__ __launch_bounds__(512) void k_bcsr(
    const int* __restrict__ off1, const int* __restrict__ off2,
    const unsigned* bkt1, const unsigned* bkt2,
    int* csr1, int* csr2,
    int* __restrict__ rp1, int* __restrict__ rp2, int E, int N, int nbkt) {
  const int* off      = blockIdx.y ? off2 : off1;
  const unsigned* bkt = blockIdx.y ? bkt2 : bkt1;
  int* csr            = blockIdx.y ? csr2 : csr1;
  int* rowptr         = blockIdx.y ? rp2 : rp1;

  const int b = blockIdx.x, t = threadIdx.x;
  const int base = off[b * NBLK];
  const int endp = (b == nbkt - 1) ? E : off[(b + 1) * NBLK];
  const int cnt  = endp - base;

  __shared__ int hist[512];
  __shared__ int sc[512];
  __shared__ int cur[512];
  __shared__ int stage[BKT_CAP];

  hist[t] = 0;
  __syncthreads();
  for (int i = t; i < cnt; i += 512)
    atomicAdd(&hist[bkt[base + i] >> 20], 1);
  __syncthreads();

  int v = hist[t];
  sc[t] = v;
  __syncthreads();
  for (int off_ = 1; off_ < 512; off_ <<= 1) {
    int add = (t >= off_) ? sc[t - off_] : 0;
    __syncthreads();
    sc[t] += add;
    __syncthreads();
  }
  int excl = sc[t] - v;

  int node = (b << BKT_SH) + t;
  if (node < N) rowptr[node] = base + excl;
  if (b == nbkt - 1 && t == 0) rowptr[N] = E;
  cur[t] = excl;
  __syncthreads();

  for (int i = t; i < cnt; i += 512) {
    unsigned u = bkt[base + i];
    int slot = atomicAdd(&cur[u >> 20], 1);
    if (slot < BKT_CAP) stage[slot] = (int)(u & 0xFFFFFu);
  }
  __syncthreads();
  for (int i = t; i < cnt; i += 512)
    csr[base + i] = stage[i];
}

// ---------------- layer-1 mean; 4-way unrolled gather ----------------
__global__ void k_agg1(bf16_t* __restrict__ xcat, const int* __restrict__ rowptr,
                       const int* __restrict__ csr, int N) {
  int t = blockIdx.x * 256 + threadIdx.x;
  int node = t >> 4, l = t & 15;
  if (node >= N) return;
  int beg = rowptr[node], end = rowptr[node + 1];
  float acc[8] = {0.f, 0.f, 0.f, 0.f, 0.f, 0.f, 0.f, 0.f};
  int e = beg;
  for (; e + 4 <= end; e += 4) {
    int s0 = csr[e], s1 = csr[e + 1], s2 = csr[e + 2], s3 = csr[e + 3];
    bf16x8 v0 = *(const bf16x8*)(xcat + (size_t)s0 * 256 + l * 8);
    bf16x8 v1 = *(const bf16x8*)(xcat + (size_t)s1 * 256 + l * 8);
    bf16x8 v2 = *(const bf16x8*)(xcat + (size_t)s2 * 256 + l * 8);
    bf16x8 v3 = *(const bf16x8*)(xcat + (size_t)s3 * 256 + l * 8);
#pragma unroll
    for (int i = 0; i < 8; ++i)
      acc[i] += (float)v0[i] + (float)v1[i] + (float)v2[i] + (float)v3[i];
  }
  for (; e < end; ++e) {
    int s = csr[e];
    bf16x8 v = *(const bf16x8*)(xcat + (size_t)s * 256 + l * 8);
#pragma unroll
    for (int i = 0; i < 8; ++i) acc[i] += (float)v[i];
  }
  float rd = (end > beg) ? 1.0f / (float)(end - beg) : 0.0f;
  bf16x8 o;
#pragma unroll
  for (int i = 0; i < 8; ++i) o[i] = (bf16_t)(acc[i] * rd);
  *(bf16x8*)(xcat + (size_t)node * 256 + 128 + l * 8) = o;
}

// ---------------- fused GEMM (round-13 verbatim, best measured 41us) ---------
__global__ __launch_bounds__(256, 3) void k_fused(
    const bf16_t* __restrict__ xcat, const bf16_t* __restrict__ w1f,
    const float* __restrict__ b1, const bf16_t* __restrict__ w2f,
    const float* __restrict__ b2v, float* __restrict__ out,
    bf16_t* __restrict__ p, int N) {
  __shared__ __align__(16) char lds[32768];
  const int tid  = (int)threadIdx.x;
  const int wv   = tid >> 6;
  const int lane = tid & 63;
  const int lr   = lane & 15;
  const int lg   = lane >> 4;
  const int c0   = wv * 64;
  const int m0   = (int)blockIdx.x * 64;

  {
    const char* tb = (const char*)(xcat + (size_t)m0 * 256);
#pragma unroll
    for (int i = 0; i < 8; ++i) {
      int L   = i * 4096 + tid * 16;
      int row = L >> 9;
      int c   = L & 511;
      int so  = (row << 9) | (c ^ ((row & 7) << 4));
      __builtin_amdgcn_global_load_lds(
          (const __attribute__((address_space(1))) void*)(tb + so),
          (__attribute__((address_space(3))) void*)(lds + L), 16, 0, 0);
    }
  }

  bf16x8 wfc[4];
#pragma unroll
  for (int wb = 0; wb < 4; ++wb)
    wfc[wb] = *(const bf16x8*)(w1f + ((size_t)(0 * 4 + lg) * 256 +
                                      (c0 + wb * 16 + lr)) * 8);
  __syncthreads();

  bf16x8 axc[4];
#pragma unroll
  for (int rb = 0; rb < 4; ++rb) {
    int lrow = rb * 16 + lr;
    axc[rb] = *(const bf16x8*)(lds + lrow * 512 +
                               ((0 * 64 + lg * 16) ^ ((lrow & 7) << 4)));
  }

  f32x4 acc[4][4] = {};
#pragma unroll
  for (int ks = 0; ks < 8; ++ks) {
    bf16x8 wfn[4], axn[4];
    if (ks < 7) {
#pragma unroll
      for (int wb = 0; wb < 4; ++wb)
        wfn[wb] = *(const bf16x8*)(w1f + ((size_t)((ks + 1) * 4 + lg) * 256 +
                                          (c0 + wb * 16 + lr)) * 8);
#pragma unroll
      for (int rb = 0; rb < 4; ++rb) {
        int lrow = rb * 16 + lr;
        axn[rb] = *(const bf16x8*)(lds + lrow * 512 +
                                   (((ks + 1) * 64 + lg * 16) ^ ((lrow & 7) << 4)));
      }
    }
#pragma unroll
    for (int wb = 0; wb < 4; ++wb)
#pragma unroll
      for (int rb = 0; rb < 4; ++rb)
        acc[wb][rb] = __builtin_amdgcn_mfma_f32_16x16x32_bf16(
            wfc[wb], axc[rb], acc[wb][rb], 0, 0, 0);
    if (ks < 7) {
#pragma unroll
      for (int i = 0; i < 4; ++i) { wfc[i] = wfn[i]; axc[i] = axn[i]; }
    }
  }

  __syncthreads();

#pragma unroll
  for (int wb = 0; wb < 4; ++wb) {
    float4 b4 = *(const float4*)(b1 + c0 + wb * 16 + lg * 4);
#pragma unroll
    for (int rb = 0; rb < 4; ++rb) {
      int xrow = rb * 16 + lr;
      bf16x4 o;
      o[0] = (bf16_t)fmaxf(acc[wb][rb][0] + b4.x, 0.f);
      o[1] = (bf16_t)fmaxf(acc[wb][rb][1] + b4.y, 0.f);
      o[2] = (bf16_t)fmaxf(acc[wb][rb][2] + b4.z, 0.f);
      o[3] = (bf16_t)fmaxf(acc[wb][rb][3] + b4.w, 0.f);
      *(bf16x4*)(lds + xrow * 512 +
                 ((c0 * 2 + wb * 32 + lg * 8) ^ ((xrow & 7) << 4))) = o;
    }
  }
  __syncthreads();

  const int arow = wv * 16 + lr;
  bf16x8 hfc = *(const bf16x8*)(lds + arow * 512 +
                                ((0 * 64 + lg * 16) ^ ((arow & 7) << 4)));
  bf16x8 w2c[5];
#pragma unroll
  for (int wb = 0; wb < 5; ++wb)
    w2c[wb] = *(const bf16x8*)(w2f + ((size_t)(0 * 4 + lg) * 80 +
                                      (wb * 16 + lr)) * 8);

  f32x4 acc2[5] = {};
#pragma unroll
  for (int ks = 0; ks < 8; ++ks) {
    bf16x8 hfn, w2n[5];
    if (ks < 7) {
      hfn = *(const bf16x8*)(lds + arow * 512 +
                             (((ks + 1) * 64 + lg * 16) ^ ((arow & 7) << 4)));
#pragma unroll
      for (int wb = 0; wb < 5; ++wb)
        w2n[wb] = *(const bf16x8*)(w2f + ((size_t)((ks + 1) * 4 + lg) * 80 +
                                          (wb * 16 + lr)) * 8);
    }
#pragma unroll
    for (int wb = 0; wb < 5; ++wb)
      acc2[wb] = __builtin_amdgcn_mfma_f32_16x16x32_bf16(
          w2c[wb], hfc, acc2[wb], 0, 0, 0);
    if (ks < 7) {
      hfc = hfn;
#pragma unroll
      for (int i = 0; i < 5; ++i) w2c[i] = w2n[i];
    }
  }

  const int r = m0 + wv * 16 + lr;
  if (r < N) {
#pragma unroll
    for (int wb = 0; wb < 5; ++wb) {
      int col0 = wb * 16 + lg * 4;
      f32x4 v = acc2[wb];
      if (col0 < 40) {
        float4 b4 = *(const float4*)(b2v + col0);
        v[0] += b4.x; v[1] += b4.y; v[2] += b4.z; v[3] += b4.w;
        *(f32x4*)(out + (size_t)r * 40 + col0) = v;
      } else {
        bf16x4 o;
        o[0] = (bf16_t)v[0]; o[1] = (bf16_t)v[1];
        o[2] = (bf16_t)v[2]; o[3] = (bf16_t)v[3];
        *(bf16x4*)(p + (size_t)r * 40 + (col0 - 40)) = o;
      }
    }
  }
}

// ---------------- layer-2 mean: out += mean2(p); 4-way unrolled bf16 gather ---
__global__ void k_agg2fin(const bf16_t* __restrict__ p, const int* __restrict__ rowptr,
                          const int* __restrict__ csr, float* __restrict__ out, int N) {
  int t = blockIdx.x * 256 + threadIdx.x;
  int node = t / 10, l = t - node * 10;
  if (node >= N) return;
  int beg = rowptr[node], end = rowptr[node + 1];
  float a0 = 0.f, a1 = 0.f, a2 = 0.f, a3 = 0.f;
  int e = beg;
  for (; e + 4 <= end; e += 4) {
    int s0 = csr[e], s1 = csr[e + 1], s2 = csr[e + 2], s3 = csr[e + 3];
    bf16x4 v0 = *(const bf16x4*)(p + (size_t)s0 * 40 + l * 4);
    bf16x4 v1 = *(const bf16x4*)(p + (size_t)s1 * 40 + l * 4);
    bf16x4 v2 = *(const bf16x4*)(p + (size_t)s2 * 40 + l * 4);
    bf16x4 v3 = *(const bf16x4*)(p + (size_t)s3 * 40 + l * 4);
    a0 += (float)v0[0] + (float)v1[0] + (float)v2[0] + (float)v3[0];
    a1 += (float)v0[1] + (float)v1[1] + (float)v2[1] + (float)v3[1];
    a2 += (float)v0[2] + (float)v1[2] + (float)v2[2] + (float)v3[2];
    a3 += (float)v0[3] + (float)v1[3] + (float)v2[3] + (float)v3[3];
  }
  for (; e < end; ++e) {
    int s = csr[e];
    bf16x4 v = *(const bf16x4*)(p + (size_t)s * 40 + l * 4);
    a0 += (float)v[0]; a1 += (float)v[1]; a2 += (float)v[2]; a3 += (float)v[3];
  }
  float rd = (end > beg) ? 1.0f / (float)(end - beg) : 0.0f;
  float* o = out + (size_t)node * 40 + l * 4;
  float4 cur = *(const float4*)o;
  cur.x += a0 * rd;
  cur.y += a1 * rd;
  cur.z += a2 * rd;
  cur.w += a3 * rd;
  *(float4*)o = cur;
}

extern "C" void kernel_launch(void* const* d_in, const int* in_sizes, int n_in,
                              void* d_out, int out_size, void* d_ws, size_t ws_size,
                              hipStream_t stream) {
  const float* x    = (const float*)d_in[0];
  const int*   src1 = (const int*)d_in[1];
  const int*   dst1 = (const int*)d_in[2];
  const int*   src2 = (const int*)d_in[3];
  const int*   dst2 = (const int*)d_in[4];
  const float* ws1  = (const float*)d_in[5];
  const float* wn1  = (const float*)d_in[6];
  const float* b1   = (const float*)d_in[7];
  const float* ws2  = (const float*)d_in[8];
  const float* wn2  = (const float*)d_in[9];
  const float* b2   = (const float*)d_in[10];
  float*       out  = (float*)d_out;

  const int N = in_sizes[0] / D_IN;
  const int E = in_sizes[1];
  if (ws_size < WS_NEEDED) return;

  char*     ws   = (char*)d_ws;
  int*      hg1  = (int*)(ws + HG1_OFF);
  int*      hg2  = (int*)(ws + HG2_OFF);
  int*      bs1  = (int*)(ws + BS1_OFF);
  int*      bs2  = (int*)(ws + BS2_OFF);
  int*      rp1  = (int*)(ws + RP1_OFF);
  int*      rp2  = (int*)(ws + RP2_OFF);
  unsigned* bkt1 = (unsigned*)(ws + BKT1_OFF);
  unsigned* bkt2 = (unsigned*)(ws + BKT2_OFF);
  int*      csr1 = (int*)(ws + BKT1_OFF);     // aliases bkt1 (safe: see k_bcsr)
  int*      csr2 = (int*)(ws + BKT2_OFF);     // aliases bkt2
  bf16_t*   xcat = (bf16_t*)(ws + XCAT_OFF);
  bf16_t*   p    = (bf16_t*)(ws + P_OFF);
  bf16_t*   w1f  = (bf16_t*)(ws + W1F_OFF);
  bf16_t*   w2f  = (bf16_t*)(ws + W2F_OFF);

  const int nbkt  = (N + 511) >> BKT_SH;       // 196
  const int chunk = (E + NBLK - 1) / NBLK;     // 9375
  const int nsc   = nbkt * NBLK;               // 12544
  const int nscb  = (nsc + 255) / 256;         // 49 (<=256)
  const int nconvx = (N * 16 + 255) / 256;     // 6250
  const int ntiles = (N + 63) / 64;            // 1563

  k_prep<<<nconvx + 32 + 2 * NBLK, 256, 0, stream>>>(
      x, xcat, ws1, wn1, ws2, wn2, w1f, w2f, dst1, dst2, hg1, hg2,
      N, E, chunk, nbkt, nconvx);

  k_scan_block<<<dim3(nscb, 2), 256, 0, stream>>>(hg1, hg2, bs1, bs2, nsc);
  k_scan_addsums<<<dim3(nscb, 2), 256, 0, stream>>>(hg1, hg2, bs1, bs2, nsc, nscb);
  k_scat<<<dim3(NBLK, 2), 256, 0, stream>>>(src1, dst1, src2, dst2, hg1, hg2,
                                            bkt1, bkt2, E, chunk, nbkt);
  k_bcsr<<<dim3(nbkt, 2), 512, 0, stream>>>(hg1, hg2, bkt1, bkt2, csr1, csr2,
                                            rp1, rp2, E, N, nbkt);

  k_agg1<<<(N * 16 + 255) / 256, 256, 0, stream>>>(xcat, rp1, csr1, N);
  k_fused<<<ntiles, 256, 0, stream>>>(xcat, w1f, b1, w2f, b2, out, p, N);
  k_agg2fin<<<(N * 10 + 255) / 256, 256, 0, stream>>>(p, rp2, csr2, out, N);
}

// Round 16
// 141.186 us; speedup vs baseline: 1.0596x; 1.0596x over previous
//
#include <hip/hip_runtime.h>
#include <hip/hip_bf16.h>
#include <cstdint>
#include <cstddef>

// ---------------------------------------------------------------------------
// GraphSAGE 2-layer forward (mean aggregator), MI355X / gfx950.
//
//   h  = relu(x @ Ws1.T + mean_nbr1(x) @ Wn1.T + b1)
//   out = h @ Ws2.T + mean_nbr2(h) @ Wn2.T + b2
//
// Structure (round 16) == round 13 (best measured, 136.5us) except k_fused
// is launched as TWO half-grid dispatches so rocprof's top-5 finally reveals
// the second-tier kernels (15 rounds of top-5 showed only k_fused).
//
// Round-1: fp32-atomic scatter = atomic-bound -> CSR gather.
// Round-3: global-atomic CSR fill = HBM RMW -> LDS counting sort.
// Round-5..14: k_fused CONVERGED ~41us (ten variants, MfmaUtil*dur = 6.3us
//   compute floor in all). r13 config best: 64-row tile, (256,3), depth-2.
// Round-15: coarser sort buckets REGRESSED (halved thread count of hist/scat;
//   parallelism > write-run length for latency-bound scatter). Reverted.
// ---------------------------------------------------------------------------

#define D_IN 128
#define D_H  256
#define D_C  40

#define NBLK     128
#define NBKT_MAX 392
#define BKT_CAP  2560

typedef __bf16 bf16_t;
typedef __attribute__((ext_vector_type(8))) __bf16 bf16x8;
typedef __attribute__((ext_vector_type(4))) __bf16 bf16x4;
typedef __attribute__((ext_vector_type(4))) float  f32x4;

// ---------------- ws layout (bytes), 256B-aligned ----------------
static constexpr size_t NMAX = 100000;
static constexpr size_t EMAX = 600000;
static constexpr size_t NSC_MAX = (size_t)NBKT_MAX * NBLK;
static constexpr size_t alignup(size_t v) { return (v + 255) & ~size_t(255); }

static constexpr size_t HG1_OFF  = 0;
static constexpr size_t HG2_OFF  = alignup(HG1_OFF + NSC_MAX * 4);
static constexpr size_t BS1_OFF  = alignup(HG2_OFF + NSC_MAX * 4);
static constexpr size_t BS2_OFF  = alignup(BS1_OFF + 512 * 4);
static constexpr size_t RP1_OFF  = alignup(BS2_OFF + 512 * 4);
static constexpr size_t RP2_OFF  = alignup(RP1_OFF + (NMAX + 1) * 4);
static constexpr size_t BKT1_OFF = alignup(RP2_OFF + (NMAX + 1) * 4);
static constexpr size_t BKT2_OFF = alignup(BKT1_OFF + EMAX * 4);
static constexpr size_t XCAT_OFF = alignup(BKT2_OFF + EMAX * 4);        // bf16[N+64][256]
static constexpr size_t P_OFF    = alignup(XCAT_OFF + (NMAX + 64) * 256 * 2); // bf16[N][40]
static constexpr size_t W1F_OFF  = alignup(P_OFF + NMAX * 40 * 2);
static constexpr size_t W2F_OFF  = alignup(W1F_OFF + 32 * 256 * 8 * 2);
static constexpr size_t WS_NEEDED = W2F_OFF + 32 * 80 * 8 * 2;

// ---------------- merged prep: convx + conv_w + hist ----------------
__global__ __launch_bounds__(256) void k_prep(
    const float* __restrict__ x, bf16_t* __restrict__ xcat,
    const float* __restrict__ ws1, const float* __restrict__ wn1,
    const float* __restrict__ ws2, const float* __restrict__ wn2,
    bf16_t* __restrict__ w1f, bf16_t* __restrict__ w2f,
    const int* __restrict__ dst1, const int* __restrict__ dst2,
    int* __restrict__ hg1, int* __restrict__ hg2,
    int N, int E, int chunk, int nbkt, int nconvx) {
  __shared__ int h[NBKT_MAX];
  int bid = blockIdx.x;

  if (bid < nconvx) {
    int t = bid * 256 + threadIdx.x;
    if (t < N * 16) {
      int row = t >> 4, j = t & 15;
      const float* sp = x + (size_t)row * 128 + j * 8;
      float4 v0 = ((const float4*)sp)[0];
      float4 v1 = ((const float4*)sp)[1];
      bf16x8 o;
      o[0] = (bf16_t)v0.x; o[1] = (bf16_t)v0.y; o[2] = (bf16_t)v0.z; o[3] = (bf16_t)v0.w;
      o[4] = (bf16_t)v1.x; o[5] = (bf16_t)v1.y; o[6] = (bf16_t)v1.z; o[7] = (bf16_t)v1.w;
      *(bf16x8*)(xcat + (size_t)row * 256 + j * 8) = o;
    }
    return;
  }
  bid -= nconvx;

  if (bid < 32) {
    int t = bid * 256 + threadIdx.x;
    {
      int ks4g = t >> 8, col = t & 255;
      int k0 = (ks4g >> 2) * 32 + (ks4g & 3) * 8;
      bf16x8 o;
#pragma unroll
      for (int i = 0; i < 8; ++i) {
        int k = k0 + i;
        float v = (k < 128) ? ws1[col * 128 + k] : wn1[col * 128 + (k - 128)];
        o[i] = (bf16_t)v;
      }
      *(bf16x8*)(w1f + (size_t)t * 8) = o;
    }
    if (t < 32 * 80) {
      int ks4g = t / 80, col = t - ks4g * 80;
      int k0 = (ks4g >> 2) * 32 + (ks4g & 3) * 8;
      bf16x8 o;
#pragma unroll
      for (int i = 0; i < 8; ++i) {
        int k = k0 + i;
        float v = (col < 40) ? ws2[col * 256 + k] : wn2[(col - 40) * 256 + k];
        o[i] = (bf16_t)v;
      }
      *(bf16x8*)(w2f + (size_t)t * 8) = o;
    }
    return;
  }
  bid -= 32;
  {
    const int* dst = (bid >> 7) ? dst2 : dst1;
    int*       hg  = (bid >> 7) ? hg2 : hg1;
    int        cb  = bid & 127;
    for (int i = threadIdx.x; i < nbkt; i += 256) h[i] = 0;
    __syncthreads();
    int beg = cb * chunk, end = min(E, beg + chunk);
    for (int e = beg + threadIdx.x; e < end; e += 256)
      atomicAdd(&h[dst[e] >> 8], 1);
    __syncthreads();
    for (int b = threadIdx.x; b < nbkt; b += 256)
      hg[b * NBLK + cb] = h[b];
  }
}

// ---------------- scan pass 1 ----------------
__global__ void k_scan_block(int* __restrict__ a1, int* __restrict__ a2,
                             int* __restrict__ b1s, int* __restrict__ b2s, int n) {
  int* a    = blockIdx.y ? a2 : a1;
  int* bsum = blockIdx.y ? b2s : b1s;
  __shared__ int lds[256];
  int t = threadIdx.x, i = blockIdx.x * 256 + t;
  int v = (i < n) ? a[i] : 0;
  lds[t] = v;
  __syncthreads();
  for (int off = 1; off < 256; off <<= 1) {
    int add = (t >= off) ? lds[t - off] : 0;
    __syncthreads();
    lds[t] += add;
    __syncthreads();
  }
  if (i < n) a[i] = lds[t] - v;
  if (t == 255) bsum[blockIdx.x] = lds[255];
}

// ---------------- scan pass 2 (merged sums-scan + add) ----------------
__global__ void k_scan_addsums(int* __restrict__ a1, int* __restrict__ a2,
                               const int* __restrict__ b1s, const int* __restrict__ b2s,
                               int n, int nb) {
  int* a          = blockIdx.y ? a2 : a1;
  const int* bsum = blockIdx.y ? b2s : b1s;
  __shared__ int lds[256];
  int t = threadIdx.x;
  int v = (t < nb) ? bsum[t] : 0;
  lds[t] = v;
  __syncthreads();
  for (int off = 1; off < 256; off <<= 1) {
    int add = (t >= off) ? lds[t - off] : 0;
    __syncthreads();
    lds[t] += add;
    __syncthreads();
  }
  __shared__ int excl[256];
  excl[t] = lds[t] - v;
  __syncthreads();
  int i = blockIdx.x * 256 + t;
  if (i < n) a[i] += excl[i >> 8];
}

// ---------------- scatter into bucketed array (LDS cursors) ----------------
__global__ void k_scat(const int* __restrict__ src1, const int* __restrict__ dst1,
                       const int* __restrict__ src2, const int* __restrict__ dst2,
                       const int* __restrict__ off1, const int* __restrict__ off2,
                       unsigned* __restrict__ bkt1, unsigned* __restrict__ bkt2,
                       int E, int chunk, int nbkt) {
  const int* src = blockIdx.y ? src2 : src1;
  const int* dst = blockIdx.y ? dst2 : dst1;
  const int* off = blockIdx.y ? off2 : off1;
  unsigned*  bkt = blockIdx.y ? bkt2 : bkt1;
  __shared__ int cur[NBKT_MAX];
  for (int i = threadIdx.x; i < nbkt; i += 256)
    cur[i] = off[i * NBLK + blockIdx.x];
  __syncthreads();
  int beg = blockIdx.x * chunk, end = min(E, beg + chunk);
  for (int e = beg + threadIdx.x; e < end; e += 256) {
    int d = dst[e];
    int slot = atomicAdd(&cur[d >> 8], 1);
    bkt[slot] = (unsigned)src[e] | ((unsigned)(d & 255) << 24);
  }
}

// ---------------- per-bucket LDS counting sort -> CSR + rowptr ----------------
__global__ __launch_bounds__(256) void k_bcsr(
    const int* __restrict__ off1, const int* __restrict__ off2,
    const unsigned* bkt1, const unsigned* bkt2,
    int* csr1, int* csr2,
    int* __restrict__ rp1, int* __restrict__ rp2, int E, int N, int nbkt) {
  const int* off      = blockIdx.y ? off2 : off1;
  const unsigned* bkt = blockIdx.y ? bkt2 : bkt1;
  int* csr            = blockIdx.y ? csr2 : csr1;
  int* rowptr         = blockIdx.y ? rp2 : rp1;

  const int b = blockIdx.x, t = threadIdx.x;
  const int base = off[b * NBLK];
  const int endp = (b == nbkt - 1) ? E : off[(b + 1) * NBLK];
  const int cnt  = endp - base;

  __shared__ int hist[256];
  __shared__ int sc[256];
  __shared__ int cur[256];
  __shared__ int stage[BKT_CAP];

  hist[t] = 0;
  __syncthreads();
  for (int i = t; i < cnt; i += 256)
    atomicAdd(&hist[bkt[base + i] >> 24], 1);
  __syncthreads();

  int v = hist[t];
  sc[t] = v;
  __syncthreads();
  for (int off_ = 1; off_ < 256; off_ <<= 1) {
    int add = (t >= off_) ? sc[t - off_] : 0;
    __syncthreads();
    sc[t] += add;
    __syncthreads();
  }
  int excl = sc[t] - v;

  int node = b * 256 + t;
  if (node < N) rowptr[node] = base + excl;
  if (b == nbkt - 1 && t == 0) rowptr[N] = E;
  cur[t] = excl;
  __syncthreads();

  for (int i = t; i < cnt; i += 256) {
    unsigned u = bkt[base + i];
    int slot = atomicAdd(&cur[u >> 24], 1);
    if (slot < BKT_CAP) stage[slot] = (int)(u & 0xFFFFFFu);
  }
  __syncthreads();
  for (int i = t; i < cnt; i += 256)
    csr[base + i] = stage[i];
}

// ---------------- layer-1 mean; 4-way unrolled gather ----------------
__global__ void k_agg1(bf16_t* __restrict__ xcat, const int* __restrict__ rowptr,
                       const int* __restrict__ csr, int N) {
  int t = blockIdx.x * 256 + threadIdx.x;
  int node = t >> 4, l = t & 15;
  if (node >= N) return;
  int beg = rowptr[node], end = rowptr[node + 1];
  float acc[8] = {0.f, 0.f, 0.f, 0.f, 0.f, 0.f, 0.f, 0.f};
  int e = beg;
  for (; e + 4 <= end; e += 4) {
    int s0 = csr[e], s1 = csr[e + 1], s2 = csr[e + 2], s3 = csr[e + 3];
    bf16x8 v0 = *(const bf16x8*)(xcat + (size_t)s0 * 256 + l * 8);
    bf16x8 v1 = *(const bf16x8*)(xcat + (size_t)s1 * 256 + l * 8);
    bf16x8 v2 = *(const bf16x8*)(xcat + (size_t)s2 * 256 + l * 8);
    bf16x8 v3 = *(const bf16x8*)(xcat + (size_t)s3 * 256 + l * 8);
#pragma unroll
    for (int i = 0; i < 8; ++i)
      acc[i] += (float)v0[i] + (float)v1[i] + (float)v2[i] + (float)v3[i];
  }
  for (; e < end; ++e) {
    int s = csr[e];
    bf16x8 v = *(const bf16x8*)(xcat + (size_t)s * 256 + l * 8);
#pragma unroll
    for (int i = 0; i < 8; ++i) acc[i] += (float)v[i];
  }
  float rd = (end > beg) ? 1.0f / (float)(end - beg) : 0.0f;
  bf16x8 o;
#pragma unroll
  for (int i = 0; i < 8; ++i) o[i] = (bf16_t)(acc[i] * rd);
  *(bf16x8*)(xcat + (size_t)node * 256 + 128 + l * 8) = o;
}

// ---------------- fused GEMM (round-13 verbatim): 64-row tile, depth-2 -------
// tile0 = block index offset so the kernel can be launched in two halves.
__global__ __launch_bounds__(256, 3) void k_fused(
    const bf16_t* __restrict__ xcat, const bf16_t* __restrict__ w1f,
    const float* __restrict__ b1, const bf16_t* __restrict__ w2f,
    const float* __restrict__ b2v, float* __restrict__ out,
    bf16_t* __restrict__ p, int N, int tile0) {
  __shared__ __align__(16) char lds[32768];
  const int tid  = (int)threadIdx.x;
  const int wv   = tid >> 6;
  const int lane = tid & 63;
  const int lr   = lane & 15;
  const int lg   = lane >> 4;
  const int c0   = wv * 64;
  const int m0   = ((int)blockIdx.x + tile0) * 64;

  {
    const char* tb = (const char*)(xcat + (size_t)m0 * 256);
#pragma unroll
    for (int i = 0; i < 8; ++i) {
      int L   = i * 4096 + tid * 16;
      int row = L >> 9;
      int c   = L & 511;
      int so  = (row << 9) | (c ^ ((row & 7) << 4));
      __builtin_amdgcn_global_load_lds(
          (const __attribute__((address_space(1))) void*)(tb + so),
          (__attribute__((address_space(3))) void*)(lds + L), 16, 0, 0);
    }
  }

  bf16x8 wfc[4];
#pragma unroll
  for (int wb = 0; wb < 4; ++wb)
    wfc[wb] = *(const bf16x8*)(w1f + ((size_t)(0 * 4 + lg) * 256 +
                                      (c0 + wb * 16 + lr)) * 8);
  __syncthreads();

  bf16x8 axc[4];
#pragma unroll
  for (int rb = 0; rb < 4; ++rb) {
    int lrow = rb * 16 + lr;
    axc[rb] = *(const bf16x8*)(lds + lrow * 512 +
                               ((0 * 64 + lg * 16) ^ ((lrow & 7) << 4)));
  }

  f32x4 acc[4][4] = {};
#pragma unroll
  for (int ks = 0; ks < 8; ++ks) {
    bf16x8 wfn[4], axn[4];
    if (ks < 7) {
#pragma unroll
      for (int wb = 0; wb < 4; ++wb)
        wfn[wb] = *(const bf16x8*)(w1f + ((size_t)((ks + 1) * 4 + lg) * 256 +
                                          (c0 + wb * 16 + lr)) * 8);
#pragma unroll
      for (int rb = 0; rb < 4; ++rb) {
        int lrow = rb * 16 + lr;
        axn[rb] = *(const bf16x8*)(lds + lrow * 512 +
                                   (((ks + 1) * 64 + lg * 16) ^ ((lrow & 7) << 4)));
      }
    }
#pragma unroll
    for (int wb = 0; wb < 4; ++wb)
#pragma unroll
      for (int rb = 0; rb < 4; ++rb)
        acc[wb][rb] = __builtin_amdgcn_mfma_f32_16x16x32_bf16(
            wfc[wb], axc[rb], acc[wb][rb], 0, 0, 0);
    if (ks < 7) {
#pragma unroll
      for (int i = 0; i < 4; ++i) { wfc[i] = wfn[i]; axc[i] = axn[i]; }
    }
  }

  __syncthreads();

#pragma unroll
  for (int wb = 0; wb < 4; ++wb) {
    float4 b4 = *(const float4*)(b1 + c0 + wb * 16 + lg * 4);
#pragma unroll
    for (int rb = 0; rb < 4; ++rb) {
      int xrow = rb * 16 + lr;
      bf16x4 o;
      o[0] = (bf16_t)fmaxf(acc[wb][rb][0] + b4.x, 0.f);
      o[1] = (bf16_t)fmaxf(acc[wb][rb][1] + b4.y, 0.f);
      o[2] = (bf16_t)fmaxf(acc[wb][rb][2] + b4.z, 0.f);
      o[3] = (bf16_t)fmaxf(acc[wb][rb][3] + b4.w, 0.f);
      *(bf16x4*)(lds + xrow * 512 +
                 ((c0 * 2 + wb * 32 + lg * 8) ^ ((xrow & 7) << 4))) = o;
    }
  }
  __syncthreads();

  const int arow = wv * 16 + lr;
  bf16x8 hfc = *(const bf16x8*)(lds + arow * 512 +
                                ((0 * 64 + lg * 16) ^ ((arow & 7) << 4)));
  bf16x8 w2c[5];
#pragma unroll
  for (int wb = 0; wb < 5; ++wb)
    w2c[wb] = *(const bf16x8*)(w2f + ((size_t)(0 * 4 + lg) * 80 +
                                      (wb * 16 + lr)) * 8);

  f32x4 acc2[5] = {};
#pragma unroll
  for (int ks = 0; ks < 8; ++ks) {
    bf16x8 hfn, w2n[5];
    if (ks < 7) {
      hfn = *(const bf16x8*)(lds + arow * 512 +
                             (((ks + 1) * 64 + lg * 16) ^ ((arow & 7) << 4)));
#pragma unroll
      for (int wb = 0; wb < 5; ++wb)
        w2n[wb] = *(const bf16x8*)(w2f + ((size_t)((ks + 1) * 4 + lg) * 80 +
                                          (wb * 16 + lr)) * 8);
    }
#pragma unroll
    for (int wb = 0; wb < 5; ++wb)
      acc2[wb] = __builtin_amdgcn_mfma_f32_16x16x32_bf16(
          w2c[wb], hfc, acc2[wb], 0, 0, 0);
    if (ks < 7) {
      hfc = hfn;
#pragma unroll
      for (int i = 0; i < 5; ++i) w2c[i] = w2n[i];
    }
  }

  const int r = m0 + wv * 16 + lr;
  if (r < N) {
#pragma unroll
    for (int wb = 0; wb < 5; ++wb) {
      int col0 = wb * 16 + lg * 4;
      f32x4 v = acc2[wb];
      if (col0 < 40) {
        float4 b4 = *(const float4*)(b2v + col0);
        v[0] += b4.x; v[1] += b4.y; v[2] += b4.z; v[3] += b4.w;
        *(f32x4*)(out + (size_t)r * 40 + col0) = v;
      } else {
        bf16x4 o;
        o[0] = (bf16_t)v[0]; o[1] = (bf16_t)v[1];
        o[2] = (bf16_t)v[2]; o[3] = (bf16_t)v[3];
        *(bf16x4*)(p + (size_t)r * 40 + (col0 - 40)) = o;
      }
    }
  }
}

// ---------------- layer-2 mean: out += mean2(p); 4-way unrolled bf16 gather ---
__global__ void k_agg2fin(const bf16_t* __restrict__ p, const int* __restrict__ rowptr,
                          const int* __restrict__ csr, float* __restrict__ out, int N) {
  int t = blockIdx.x * 256 + threadIdx.x;
  int node = t / 10, l = t - node * 10;
  if (node >= N) return;
  int beg = rowptr[node], end = rowptr[node + 1];
  float a0 = 0.f, a1 = 0.f, a2 = 0.f, a3 = 0.f;
  int e = beg;
  for (; e + 4 <= end; e += 4) {
    int s0 = csr[e], s1 = csr[e + 1], s2 = csr[e + 2], s3 = csr[e + 3];
    bf16x4 v0 = *(const bf16x4*)(p + (size_t)s0 * 40 + l * 4);
    bf16x4 v1 = *(const bf16x4*)(p + (size_t)s1 * 40 + l * 4);
    bf16x4 v2 = *(const bf16x4*)(p + (size_t)s2 * 40 + l * 4);
    bf16x4 v3 = *(const bf16x4*)(p + (size_t)s3 * 40 + l * 4);
    a0 += (float)v0[0] + (float)v1[0] + (float)v2[0] + (float)v3[0];
    a1 += (float)v0[1] + (float)v1[1] + (float)v2[1] + (float)v3[1];
    a2 += (float)v0[2] + (float)v1[2] + (float)v2[2] + (float)v3[2];
    a3 += (float)v0[3] + (float)v1[3] + (float)v2[3] + (float)v3[3];
  }
  for (; e < end; ++e) {
    int s = csr[e];
    bf16x4 v = *(const bf16x4*)(p + (size_t)s * 40 + l * 4);
    a0 += (float)v[0]; a1 += (float)v[1]; a2 += (float)v[2]; a3 += (float)v[3];
  }
  float rd = (end > beg) ? 1.0f / (float)(end - beg) : 0.0f;
  float* o = out + (size_t)node * 40 + l * 4;
  float4 cur = *(const float4*)o;
  cur.x += a0 * rd;
  cur.y += a1 * rd;
  cur.z += a2 * rd;
  cur.w += a3 * rd;
  *(float4*)o = cur;
}

extern "C" void kernel_launch(void* const* d_in, const int* in_sizes, int n_in,
                              void* d_out, int out_size, void* d_ws, size_t ws_size,
                              hipStream_t stream) {
  const float* x    = (const float*)d_in[0];
  const int*   src1 = (const int*)d_in[1];
  const int*   dst1 = (const int*)d_in[2];
  const int*   src2 = (const int*)d_in[3];
  const int*   dst2 = (const int*)d_in[4];
  const float* ws1  = (const float*)d_in[5];
  const float* wn1  = (const float*)d_in[6];
  const float* b1   = (const float*)d_in[7];
  const float* ws2  = (const float*)d_in[8];
  const float* wn2  = (const float*)d_in[9];
  const float* b2   = (const float*)d_in[10];
  float*       out  = (float*)d_out;

  const int N = in_sizes[0] / D_IN;
  const int E = in_sizes[1];
  if (ws_size < WS_NEEDED) return;

  char*     ws   = (char*)d_ws;
  int*      hg1  = (int*)(ws + HG1_OFF);
  int*      hg2  = (int*)(ws + HG2_OFF);
  int*      bs1  = (int*)(ws + BS1_OFF);
  int*      bs2  = (int*)(ws + BS2_OFF);
  int*      rp1  = (int*)(ws + RP1_OFF);
  int*      rp2  = (int*)(ws + RP2_OFF);
  unsigned* bkt1 = (unsigned*)(ws + BKT1_OFF);
  unsigned* bkt2 = (unsigned*)(ws + BKT2_OFF);
  int*      csr1 = (int*)(ws + BKT1_OFF);     // aliases bkt1 (safe: see k_bcsr)
  int*      csr2 = (int*)(ws + BKT2_OFF);     // aliases bkt2
  bf16_t*   xcat = (bf16_t*)(ws + XCAT_OFF);
  bf16_t*   p    = (bf16_t*)(ws + P_OFF);
  bf16_t*   w1f  = (bf16_t*)(ws + W1F_OFF);
  bf16_t*   w2f  = (bf16_t*)(ws + W2F_OFF);

  const int nbkt  = (N + 255) >> 8;            // 391
  const int chunk = (E + NBLK - 1) / NBLK;     // 4688
  const int nsc   = nbkt * NBLK;               // 50048
  const int nscb  = (nsc + 255) / 256;         // 196 (<=256)
  const int nconvx = (N * 16 + 255) / 256;     // 6250
  const int ntiles = (N + 63) / 64;            // 1563

  k_prep<<<nconvx + 32 + 2 * NBLK, 256, 0, stream>>>(
      x, xcat, ws1, wn1, ws2, wn2, w1f, w2f, dst1, dst2, hg1, hg2,
      N, E, chunk, nbkt, nconvx);

  k_scan_block<<<dim3(nscb, 2), 256, 0, stream>>>(hg1, hg2, bs1, bs2, nsc);
  k_scan_addsums<<<dim3(nscb, 2), 256, 0, stream>>>(hg1, hg2, bs1, bs2, nsc, nscb);
  k_scat<<<dim3(NBLK, 2), 256, 0, stream>>>(src1, dst1, src2, dst2, hg1, hg2,
                                            bkt1, bkt2, E, chunk, nbkt);
  k_bcsr<<<dim3(nbkt, 2), 256, 0, stream>>>(hg1, hg2, bkt1, bkt2, csr1, csr2,
                                            rp1, rp2, E, N, nbkt);

  k_agg1<<<(N * 16 + 255) / 256, 256, 0, stream>>>(xcat, rp1, csr1, N);
  {
    int half = (ntiles + 1) / 2;               // two dispatches: makes the
    k_fused<<<half, 256, 0, stream>>>(xcat, w1f, b1, w2f, b2, out, p, N, 0);
    k_fused<<<ntiles - half, 256, 0, stream>>>(xcat, w1f, b1, w2f, b2, out, p, N, half);
  }
  k_agg2fin<<<(N * 10 + 255) / 256, 256, 0, stream>>>(p, rp2, csr2, out, N);
}

// Round 17
// 132.747 us; speedup vs baseline: 1.1270x; 1.0636x over previous
//
#include <hip/hip_runtime.h>
#include <hip/hip_bf16.h>
#include <cstdint>
#include <cstddef>

// ---------------------------------------------------------------------------
// GraphSAGE 2-layer forward (mean aggregator), MI355X / gfx950.
//
//   h  = relu(x @ Ws1.T + mean_nbr1(x) @ Wn1.T + b1)
//   out = h @ Ws2.T + mean_nbr2(h) @ Wn2.T + b2
//
// Structure (round 17):
//   k_prep:       xcat[:,0:128]=bf16(x); w1f/w2f frag-major; LDS histograms
//   k_scan_block: per-256-chunk exclusive scan + chunk totals (bs)
//   k_scat:       INLINE bs-scan in LDS -> offsets; LDS-cursor scatter
//   k_bcsr:       INLINE bs-scan -> bucket base; LDS counting sort -> CSR
//   k_agg1:       mean1 gather with MASKED 4-BATCHES (clamped idx + 0/1
//                 mask: every node gets ceil(deg/4) parallel batches, no
//                 serial tail)
//   k_fused:      round-13 verbatim single dispatch (best: 41us)
//   k_agg2fin:    out += mean2(p), masked 4-batches
//
// Round-1: fp32-atomic scatter = atomic-bound -> CSR gather.
// Round-3: global-atomic CSR fill = HBM RMW -> LDS counting sort.
// Round-5..14: k_fused CONVERGED ~41us (ten variants; MfmaUtil*dur = 6.3us
//   = compute floor in all). r13 config best.
// Round-15: coarser sort buckets regressed (parallelism > run length).
// Round-16: split-dispatch cost 4.7us; top-5 revealed only harness poison
//   fills (268MB, not ours) -> all non-fused kernels < 39us. This round:
//   cut launch count (merge sums-scan) + kill gather serial tails.
// ---------------------------------------------------------------------------

#define D_IN 128
#define D_H  256
#define D_C  40

#define NBLK     128
#define NBKT_MAX 392
#define BKT_CAP  2560

typedef __bf16 bf16_t;
typedef __attribute__((ext_vector_type(8))) __bf16 bf16x8;
typedef __attribute__((ext_vector_type(4))) __bf16 bf16x4;
typedef __attribute__((ext_vector_type(4))) float  f32x4;

// ---------------- ws layout (bytes), 256B-aligned ----------------
static constexpr size_t NMAX = 100000;
static constexpr size_t EMAX = 600000;
static constexpr size_t NSC_MAX = (size_t)NBKT_MAX * NBLK;
static constexpr size_t alignup(size_t v) { return (v + 255) & ~size_t(255); }

static constexpr size_t HG1_OFF  = 0;
static constexpr size_t HG2_OFF  = alignup(HG1_OFF + NSC_MAX * 4);
static constexpr size_t BS1_OFF  = alignup(HG2_OFF + NSC_MAX * 4);
static constexpr size_t BS2_OFF  = alignup(BS1_OFF + 512 * 4);
static constexpr size_t RP1_OFF  = alignup(BS2_OFF + 512 * 4);
static constexpr size_t RP2_OFF  = alignup(RP1_OFF + (NMAX + 1) * 4);
static constexpr size_t BKT1_OFF = alignup(RP2_OFF + (NMAX + 1) * 4);
static constexpr size_t BKT2_OFF = alignup(BKT1_OFF + EMAX * 4);
static constexpr size_t XCAT_OFF = alignup(BKT2_OFF + EMAX * 4);        // bf16[N+64][256]
static constexpr size_t P_OFF    = alignup(XCAT_OFF + (NMAX + 64) * 256 * 2); // bf16[N][40]
static constexpr size_t W1F_OFF  = alignup(P_OFF + NMAX * 40 * 2);
static constexpr size_t W2F_OFF  = alignup(W1F_OFF + 32 * 256 * 8 * 2);
static constexpr size_t WS_NEEDED = W2F_OFF + 32 * 80 * 8 * 2;

// ---------------- merged prep: convx + conv_w + hist ----------------
__global__ __launch_bounds__(256) void k_prep(
    const float* __restrict__ x, bf16_t* __restrict__ xcat,
    const float* __restrict__ ws1, const float* __restrict__ wn1,
    const float* __restrict__ ws2, const float* __restrict__ wn2,
    bf16_t* __restrict__ w1f, bf16_t* __restrict__ w2f,
    const int* __restrict__ dst1, const int* __restrict__ dst2,
    int* __restrict__ hg1, int* __restrict__ hg2,
    int N, int E, int chunk, int nbkt, int nconvx) {
  __shared__ int h[NBKT_MAX];
  int bid = blockIdx.x;

  if (bid < nconvx) {
    int t = bid * 256 + threadIdx.x;
    if (t < N * 16) {
      int row = t >> 4, j = t & 15;
      const float* sp = x + (size_t)row * 128 + j * 8;
      float4 v0 = ((const float4*)sp)[0];
      float4 v1 = ((const float4*)sp)[1];
      bf16x8 o;
      o[0] = (bf16_t)v0.x; o[1] = (bf16_t)v0.y; o[2] = (bf16_t)v0.z; o[3] = (bf16_t)v0.w;
      o[4] = (bf16_t)v1.x; o[5] = (bf16_t)v1.y; o[6] = (bf16_t)v1.z; o[7] = (bf16_t)v1.w;
      *(bf16x8*)(xcat + (size_t)row * 256 + j * 8) = o;
    }
    return;
  }
  bid -= nconvx;

  if (bid < 32) {
    int t = bid * 256 + threadIdx.x;
    {
      int ks4g = t >> 8, col = t & 255;
      int k0 = (ks4g >> 2) * 32 + (ks4g & 3) * 8;
      bf16x8 o;
#pragma unroll
      for (int i = 0; i < 8; ++i) {
        int k = k0 + i;
        float v = (k < 128) ? ws1[col * 128 + k] : wn1[col * 128 + (k - 128)];
        o[i] = (bf16_t)v;
      }
      *(bf16x8*)(w1f + (size_t)t * 8) = o;
    }
    if (t < 32 * 80) {
      int ks4g = t / 80, col = t - ks4g * 80;
      int k0 = (ks4g >> 2) * 32 + (ks4g & 3) * 8;
      bf16x8 o;
#pragma unroll
      for (int i = 0; i < 8; ++i) {
        int k = k0 + i;
        float v = (col < 40) ? ws2[col * 256 + k] : wn2[(col - 40) * 256 + k];
        o[i] = (bf16_t)v;
      }
      *(bf16x8*)(w2f + (size_t)t * 8) = o;
    }
    return;
  }
  bid -= 32;
  {
    const int* dst = (bid >> 7) ? dst2 : dst1;
    int*       hg  = (bid >> 7) ? hg2 : hg1;
    int        cb  = bid & 127;
    for (int i = threadIdx.x; i < nbkt; i += 256) h[i] = 0;
    __syncthreads();
    int beg = cb * chunk, end = min(E, beg + chunk);
    for (int e = beg + threadIdx.x; e < end; e += 256)
      atomicAdd(&h[dst[e] >> 8], 1);
    __syncthreads();
    for (int b = threadIdx.x; b < nbkt; b += 256)
      hg[b * NBLK + cb] = h[b];
  }
}

// ---------------- scan pass 1: per-256-chunk excl scan + chunk totals --------
__global__ void k_scan_block(int* __restrict__ a1, int* __restrict__ a2,
                             int* __restrict__ b1s, int* __restrict__ b2s, int n) {
  int* a    = blockIdx.y ? a2 : a1;
  int* bsum = blockIdx.y ? b2s : b1s;
  __shared__ int lds[256];
  int t = threadIdx.x, i = blockIdx.x * 256 + t;
  int v = (i < n) ? a[i] : 0;
  lds[t] = v;
  __syncthreads();
  for (int off = 1; off < 256; off <<= 1) {
    int add = (t >= off) ? lds[t - off] : 0;
    __syncthreads();
    lds[t] += add;
    __syncthreads();
  }
  if (i < n) a[i] = lds[t] - v;
  if (t == 255) bsum[blockIdx.x] = lds[255];
}

// ---------------- scatter (inline bs-scan -> offsets; LDS cursors) ----------
__global__ void k_scat(const int* __restrict__ src1, const int* __restrict__ dst1,
                       const int* __restrict__ src2, const int* __restrict__ dst2,
                       const int* __restrict__ hg1, const int* __restrict__ hg2,
                       const int* __restrict__ b1s, const int* __restrict__ b2s,
                       unsigned* __restrict__ bkt1, unsigned* __restrict__ bkt2,
                       int E, int chunk, int nbkt, int nb) {
  const int* src = blockIdx.y ? src2 : src1;
  const int* dst = blockIdx.y ? dst2 : dst1;
  const int* hg  = blockIdx.y ? hg2 : hg1;
  const int* bs  = blockIdx.y ? b2s : b1s;
  unsigned*  bkt = blockIdx.y ? bkt2 : bkt1;
  const int cb = blockIdx.x, t = threadIdx.x;

  __shared__ int sbuf[256];
  __shared__ int sexcl[256];
  __shared__ int cur[NBKT_MAX];

  int v = (t < nb) ? bs[t] : 0;
  sbuf[t] = v;
  __syncthreads();
  for (int off = 1; off < 256; off <<= 1) {
    int add = (t >= off) ? sbuf[t - off] : 0;
    __syncthreads();
    sbuf[t] += add;
    __syncthreads();
  }
  sexcl[t] = sbuf[t] - v;
  __syncthreads();
  for (int i = t; i < nbkt; i += 256) {
    int idx = i * NBLK + cb;
    cur[i] = hg[idx] + sexcl[idx >> 8];
  }
  __syncthreads();

  int beg = cb * chunk, end = min(E, beg + chunk);
  for (int e = beg + t; e < end; e += 256) {
    int d = dst[e];
    int slot = atomicAdd(&cur[d >> 8], 1);
    bkt[slot] = (unsigned)src[e] | ((unsigned)(d & 255) << 24);
  }
}

// ---------------- per-bucket LDS counting sort -> CSR + rowptr ----------------
__global__ __launch_bounds__(256) void k_bcsr(
    const int* __restrict__ hg1, const int* __restrict__ hg2,
    const int* __restrict__ b1s, const int* __restrict__ b2s,
    const unsigned* bkt1, const unsigned* bkt2,
    int* csr1, int* csr2,
    int* __restrict__ rp1, int* __restrict__ rp2, int E, int N, int nbkt, int nb) {
  const int* hg       = blockIdx.y ? hg2 : hg1;
  const int* bs       = blockIdx.y ? b2s : b1s;
  const unsigned* bkt = blockIdx.y ? bkt2 : bkt1;
  int* csr            = blockIdx.y ? csr2 : csr1;
  int* rowptr         = blockIdx.y ? rp2 : rp1;

  const int b = blockIdx.x, t = threadIdx.x;

  __shared__ int sbuf[256];
  __shared__ int hist[256];
  __shared__ int sc[256];
  __shared__ int cur[256];
  __shared__ int stage[BKT_CAP];
  __shared__ int s_base, s_endp;

  // inline bs-scan to recover bucket base offsets
  int v0 = (t < nb) ? bs[t] : 0;
  sbuf[t] = v0;
  __syncthreads();
  for (int off_ = 1; off_ < 256; off_ <<= 1) {
    int add = (t >= off_) ? sbuf[t - off_] : 0;
    __syncthreads();
    sbuf[t] += add;
    __syncthreads();
  }
  if (t == 0) {
    int i0 = b * NBLK;
    int e0 = sbuf[i0 >> 8] - ((i0 >> 8) < nb ? bs[i0 >> 8] : 0);
    s_base = hg[i0] + e0;
    if (b == nbkt - 1) {
      s_endp = E;
    } else {
      int i1 = (b + 1) * NBLK;
      int e1 = sbuf[i1 >> 8] - ((i1 >> 8) < nb ? bs[i1 >> 8] : 0);
      s_endp = hg[i1] + e1;
    }
  }
  hist[t] = 0;
  __syncthreads();
  const int base = s_base, endp = s_endp;
  const int cnt  = endp - base;

  for (int i = t; i < cnt; i += 256)
    atomicAdd(&hist[bkt[base + i] >> 24], 1);
  __syncthreads();

  int v = hist[t];
  sc[t] = v;
  __syncthreads();
  for (int off_ = 1; off_ < 256; off_ <<= 1) {
    int add = (t >= off_) ? sc[t - off_] : 0;
    __syncthreads();
    sc[t] += add;
    __syncthreads();
  }
  int excl = sc[t] - v;

  int node = b * 256 + t;
  if (node < N) rowptr[node] = base + excl;
  if (b == nbkt - 1 && t == 0) rowptr[N] = E;
  cur[t] = excl;
  __syncthreads();

  for (int i = t; i < cnt; i += 256) {
    unsigned u = bkt[base + i];
    int slot = atomicAdd(&cur[u >> 24], 1);
    if (slot < BKT_CAP) stage[slot] = (int)(u & 0xFFFFFFu);
  }
  __syncthreads();
  for (int i = t; i < cnt; i += 256)
    csr[base + i] = stage[i];
}

// ---------------- layer-1 mean; MASKED 4-batch gather ----------------
// Clamped indices + 0/1 masks: every node = ceil(deg/4) fully-parallel
// batches (4 loads in flight), no serial tail.
__global__ void k_agg1(bf16_t* __restrict__ xcat, const int* __restrict__ rowptr,
                       const int* __restrict__ csr, int N) {
  int t = blockIdx.x * 256 + threadIdx.x;
  int node = t >> 4, l = t & 15;
  if (node >= N) return;
  int beg = rowptr[node], end = rowptr[node + 1];
  float acc[8] = {0.f, 0.f, 0.f, 0.f, 0.f, 0.f, 0.f, 0.f};
  for (int e = beg; e < end; e += 4) {
    int e1 = e + 1 < end ? e + 1 : e;
    int e2 = e + 2 < end ? e + 2 : e;
    int e3 = e + 3 < end ? e + 3 : e;
    float m1 = e + 1 < end ? 1.f : 0.f;
    float m2 = e + 2 < end ? 1.f : 0.f;
    float m3 = e + 3 < end ? 1.f : 0.f;
    int s0 = csr[e], s1 = csr[e1], s2 = csr[e2], s3 = csr[e3];
    bf16x8 v0 = *(const bf16x8*)(xcat + (size_t)s0 * 256 + l * 8);
    bf16x8 v1 = *(const bf16x8*)(xcat + (size_t)s1 * 256 + l * 8);
    bf16x8 v2 = *(const bf16x8*)(xcat + (size_t)s2 * 256 + l * 8);
    bf16x8 v3 = *(const bf16x8*)(xcat + (size_t)s3 * 256 + l * 8);
#pragma unroll
    for (int i = 0; i < 8; ++i)
      acc[i] += (float)v0[i] + m1 * (float)v1[i] + m2 * (float)v2[i] + m3 * (float)v3[i];
  }
  float rd = (end > beg) ? 1.0f / (float)(end - beg) : 0.0f;
  bf16x8 o;
#pragma unroll
  for (int i = 0; i < 8; ++i) o[i] = (bf16_t)(acc[i] * rd);
  *(bf16x8*)(xcat + (size_t)node * 256 + 128 + l * 8) = o;
}

// ---------------- fused GEMM (round-13 verbatim): 64-row tile, depth-2 -------
__global__ __launch_bounds__(256, 3) void k_fused(
    const bf16_t* __restrict__ xcat, const bf16_t* __restrict__ w1f,
    const float* __restrict__ b1, const bf16_t* __restrict__ w2f,
    const float* __restrict__ b2v, float* __restrict__ out,
    bf16_t* __restrict__ p, int N) {
  __shared__ __align__(16) char lds[32768];
  const int tid  = (int)threadIdx.x;
  const int wv   = tid >> 6;
  const int lane = tid & 63;
  const int lr   = lane & 15;
  const int lg   = lane >> 4;
  const int c0   = wv * 64;
  const int m0   = (int)blockIdx.x * 64;

  {
    const char* tb = (const char*)(xcat + (size_t)m0 * 256);
#pragma unroll
    for (int i = 0; i < 8; ++i) {
      int L   = i * 4096 + tid * 16;
      int row = L >> 9;
      int c   = L & 511;
      int so  = (row << 9) | (c ^ ((row & 7) << 4));
      __builtin_amdgcn_global_load_lds(
          (const __attribute__((address_space(1))) void*)(tb + so),
          (__attribute__((address_space(3))) void*)(lds + L), 16, 0, 0);
    }
  }

  bf16x8 wfc[4];
#pragma unroll
  for (int wb = 0; wb < 4; ++wb)
    wfc[wb] = *(const bf16x8*)(w1f + ((size_t)(0 * 4 + lg) * 256 +
                                      (c0 + wb * 16 + lr)) * 8);
  __syncthreads();

  bf16x8 axc[4];
#pragma unroll
  for (int rb = 0; rb < 4; ++rb) {
    int lrow = rb * 16 + lr;
    axc[rb] = *(const bf16x8*)(lds + lrow * 512 +
                               ((0 * 64 + lg * 16) ^ ((lrow & 7) << 4)));
  }

  f32x4 acc[4][4] = {};
#pragma unroll
  for (int ks = 0; ks < 8; ++ks) {
    bf16x8 wfn[4], axn[4];
    if (ks < 7) {
#pragma unroll
      for (int wb = 0; wb < 4; ++wb)
        wfn[wb] = *(const bf16x8*)(w1f + ((size_t)((ks + 1) * 4 + lg) * 256 +
                                          (c0 + wb * 16 + lr)) * 8);
#pragma unroll
      for (int rb = 0; rb < 4; ++rb) {
        int lrow = rb * 16 + lr;
        axn[rb] = *(const bf16x8*)(lds + lrow * 512 +
                                   (((ks + 1) * 64 + lg * 16) ^ ((lrow & 7) << 4)));
      }
    }
#pragma unroll
    for (int wb = 0; wb < 4; ++wb)
#pragma unroll
      for (int rb = 0; rb < 4; ++rb)
        acc[wb][rb] = __builtin_amdgcn_mfma_f32_16x16x32_bf16(
            wfc[wb], axc[rb], acc[wb][rb], 0, 0, 0);
    if (ks < 7) {
#pragma unroll
      for (int i = 0; i < 4; ++i) { wfc[i] = wfn[i]; axc[i] = axn[i]; }
    }
  }

  __syncthreads();

#pragma unroll
  for (int wb = 0; wb < 4; ++wb) {
    float4 b4 = *(const float4*)(b1 + c0 + wb * 16 + lg * 4);
#pragma unroll
    for (int rb = 0; rb < 4; ++rb) {
      int xrow = rb * 16 + lr;
      bf16x4 o;
      o[0] = (bf16_t)fmaxf(acc[wb][rb][0] + b4.x, 0.f);
      o[1] = (bf16_t)fmaxf(acc[wb][rb][1] + b4.y, 0.f);
      o[2] = (bf16_t)fmaxf(acc[wb][rb][2] + b4.z, 0.f);
      o[3] = (bf16_t)fmaxf(acc[wb][rb][3] + b4.w, 0.f);
      *(bf16x4*)(lds + xrow * 512 +
                 ((c0 * 2 + wb * 32 + lg * 8) ^ ((xrow & 7) << 4))) = o;
    }
  }
  __syncthreads();

  const int arow = wv * 16 + lr;
  bf16x8 hfc = *(const bf16x8*)(lds + arow * 512 +
                                ((0 * 64 + lg * 16) ^ ((arow & 7) << 4)));
  bf16x8 w2c[5];
#pragma unroll
  for (int wb = 0; wb < 5; ++wb)
    w2c[wb] = *(const bf16x8*)(w2f + ((size_t)(0 * 4 + lg) * 80 +
                                      (wb * 16 + lr)) * 8);

  f32x4 acc2[5] = {};
#pragma unroll
  for (int ks = 0; ks < 8; ++ks) {
    bf16x8 hfn, w2n[5];
    if (ks < 7) {
      hfn = *(const bf16x8*)(lds + arow * 512 +
                             (((ks + 1) * 64 + lg * 16) ^ ((arow & 7) << 4)));
#pragma unroll
      for (int wb = 0; wb < 5; ++wb)
        w2n[wb] = *(const bf16x8*)(w2f + ((size_t)((ks + 1) * 4 + lg) * 80 +
                                          (wb * 16 + lr)) * 8);
    }
#pragma unroll
    for (int wb = 0; wb < 5; ++wb)
      acc2[wb] = __builtin_amdgcn_mfma_f32_16x16x32_bf16(
          w2c[wb], hfc, acc2[wb], 0, 0, 0);
    if (ks < 7) {
      hfc = hfn;
#pragma unroll
      for (int i = 0; i < 5; ++i) w2c[i] = w2n[i];
    }
  }

  const int r = m0 + wv * 16 + lr;
  if (r < N) {
#pragma unroll
    for (int wb = 0; wb < 5; ++wb) {
      int col0 = wb * 16 + lg * 4;
      f32x4 v = acc2[wb];
      if (col0 < 40) {
        float4 b4 = *(const float4*)(b2v + col0);
        v[0] += b4.x; v[1] += b4.y; v[2] += b4.z; v[3] += b4.w;
        *(f32x4*)(out + (size_t)r * 40 + col0) = v;
      } else {
        bf16x4 o;
        o[0] = (bf16_t)v[0]; o[1] = (bf16_t)v[1];
        o[2] = (bf16_t)v[2]; o[3] = (bf16_t)v[3];
        *(bf16x4*)(p + (size_t)r * 40 + (col0 - 40)) = o;
      }
    }
  }
}

// ---------------- layer-2 mean: masked 4-batch bf16 gather ----------------
__global__ void k_agg2fin(const bf16_t* __restrict__ p, const int* __restrict__ rowptr,
                          const int* __restrict__ csr, float* __restrict__ out, int N) {
  int t = blockIdx.x * 256 + threadIdx.x;
  int node = t / 10, l = t - node * 10;
  if (node >= N) return;
  int beg = rowptr[node], end = rowptr[node + 1];
  float a0 = 0.f, a1 = 0.f, a2 = 0.f, a3 = 0.f;
  for (int e = beg; e < end; e += 4) {
    int e1 = e + 1 < end ? e + 1 : e;
    int e2 = e + 2 < end ? e + 2 : e;
    int e3 = e + 3 < end ? e + 3 : e;
    float m1 = e + 1 < end ? 1.f : 0.f;
    float m2 = e + 2 < end ? 1.f : 0.f;
    float m3 = e + 3 < end ? 1.f : 0.f;
    int s0 = csr[e], s1 = csr[e1], s2 = csr[e2], s3 = csr[e3];
    bf16x4 v0 = *(const bf16x4*)(p + (size_t)s0 * 40 + l * 4);
    bf16x4 v1 = *(const bf16x4*)(p + (size_t)s1 * 40 + l * 4);
    bf16x4 v2 = *(const bf16x4*)(p + (size_t)s2 * 40 + l * 4);
    bf16x4 v3 = *(const bf16x4*)(p + (size_t)s3 * 40 + l * 4);
    a0 += (float)v0[0] + m1 * (float)v1[0] + m2 * (float)v2[0] + m3 * (float)v3[0];
    a1 += (float)v0[1] + m1 * (float)v1[1] + m2 * (float)v2[1] + m3 * (float)v3[1];
    a2 += (float)v0[2] + m1 * (float)v1[2] + m2 * (float)v2[2] + m3 * (float)v3[2];
    a3 += (float)v0[3] + m1 * (float)v1[3] + m2 * (float)v2[3] + m3 * (float)v3[3];
  }
  float rd = (end > beg) ? 1.0f / (float)(end - beg) : 0.0f;
  float* o = out + (size_t)node * 40 + l * 4;
  float4 cur = *(const float4*)o;
  cur.x += a0 * rd;
  cur.y += a1 * rd;
  cur.z += a2 * rd;
  cur.w += a3 * rd;
  *(float4*)o = cur;
}

extern "C" void kernel_launch(void* const* d_in, const int* in_sizes, int n_in,
                              void* d_out, int out_size, void* d_ws, size_t ws_size,
                              hipStream_t stream) {
  const float* x    = (const float*)d_in[0];
  const int*   src1 = (const int*)d_in[1];
  const int*   dst1 = (const int*)d_in[2];
  const int*   src2 = (const int*)d_in[3];
  const int*   dst2 = (const int*)d_in[4];
  const float* ws1  = (const float*)d_in[5];
  const float* wn1  = (const float*)d_in[6];
  const float* b1   = (const float*)d_in[7];
  const float* ws2  = (const float*)d_in[8];
  const float* wn2  = (const float*)d_in[9];
  const float* b2   = (const float*)d_in[10];
  float*       out  = (float*)d_out;

  const int N = in_sizes[0] / D_IN;
  const int E = in_sizes[1];
  if (ws_size < WS_NEEDED) return;

  char*     ws   = (char*)d_ws;
  int*      hg1  = (int*)(ws + HG1_OFF);
  int*      hg2  = (int*)(ws + HG2_OFF);
  int*      bs1  = (int*)(ws + BS1_OFF);
  int*      bs2  = (int*)(ws + BS2_OFF);
  int*      rp1  = (int*)(ws + RP1_OFF);
  int*      rp2  = (int*)(ws + RP2_OFF);
  unsigned* bkt1 = (unsigned*)(ws + BKT1_OFF);
  unsigned* bkt2 = (unsigned*)(ws + BKT2_OFF);
  int*      csr1 = (int*)(ws + BKT1_OFF);     // aliases bkt1 (safe: see k_bcsr)
  int*      csr2 = (int*)(ws + BKT2_OFF);     // aliases bkt2
  bf16_t*   xcat = (bf16_t*)(ws + XCAT_OFF);
  bf16_t*   p    = (bf16_t*)(ws + P_OFF);
  bf16_t*   w1f  = (bf16_t*)(ws + W1F_OFF);
  bf16_t*   w2f  = (bf16_t*)(ws + W2F_OFF);

  const int nbkt  = (N + 255) >> 8;            // 391
  const int chunk = (E + NBLK - 1) / NBLK;     // 4688
  const int nsc   = nbkt * NBLK;               // 50048
  const int nscb  = (nsc + 255) / 256;         // 196 (<=256)
  const int nconvx = (N * 16 + 255) / 256;     // 6250
  const int ntiles = (N + 63) / 64;            // 1563

  k_prep<<<nconvx + 32 + 2 * NBLK, 256, 0, stream>>>(
      x, xcat, ws1, wn1, ws2, wn2, w1f, w2f, dst1, dst2, hg1, hg2,
      N, E, chunk, nbkt, nconvx);

  k_scan_block<<<dim3(nscb, 2), 256, 0, stream>>>(hg1, hg2, bs1, bs2, nsc);
  k_scat<<<dim3(NBLK, 2), 256, 0, stream>>>(src1, dst1, src2, dst2, hg1, hg2,
                                            bs1, bs2, bkt1, bkt2, E, chunk, nbkt, nscb);
  k_bcsr<<<dim3(nbkt, 2), 256, 0, stream>>>(hg1, hg2, bs1, bs2, bkt1, bkt2,
                                            csr1, csr2, rp1, rp2, E, N, nbkt, nscb);

  k_agg1<<<(N * 16 + 255) / 256, 256, 0, stream>>>(xcat, rp1, csr1, N);
  k_fused<<<ntiles, 256, 0, stream>>>(xcat, w1f, b1, w2f, b2, out, p, N);
  k_agg2fin<<<(N * 10 + 255) / 256, 256, 0, stream>>>(p, rp2, csr2, out, N);
}